// Round 3
// baseline (165.161 us; speedup 1.0000x reference)
//
#include <hip/hip_runtime.h>
#include <hip/hip_bf16.h>

#define N_NODES 100000
#define IN_DIM  128
#define HIDDEN  64
#define N_EDGES 1600000

typedef unsigned short u16;
typedef unsigned int   u32;
typedef unsigned char  u8;

typedef __attribute__((ext_vector_type(8))) short bf16x8;  // 8 bf16 in 4 VGPRs
typedef __attribute__((ext_vector_type(4))) float f32x4;
typedef __attribute__((ext_vector_type(2))) float f32x2;

__device__ __forceinline__ u16 f2bf(float f) {
    // round-to-nearest-even fp32 -> bf16
    u32 u = __float_as_uint(f);
    u32 r = 0x7FFFu + ((u >> 16) & 1u);
    u += r;
    return (u16)(u >> 16);
}

#define LDK 136          // 128 + 8 bf16 pad -> row stride 272 B (16B-aligned)
#define GEMM_BLOCKS 782  // 3128 waves -> 6250 tiles ~= 2/wave (balanced)
#define BATCH 8          // edges per wave = 16 subs * 8 batch = 128
#define EDGE_BLOCKS 3125 // 3125 * 4 waves * 128 edges = 1.6M

// ---------------------------------------------------------------------------
// Kernel 1: GEMM with prep fused in. Each block converts W1 (fp32 [256][64])
// into its LDS tile Bs[jj][k] (bf16 concat-transpose) directly -- prep kernel
// and the WcatT global round-trip eliminated (no cross-block dependency).
// GEMM phase identical to round-1 (operand-swapped MFMA, D=[hidden][node],
// packed dword fp8 epilogue) which passed at absmax 0.0078125.
// ---------------------------------------------------------------------------
__global__ __launch_bounds__(256) void gemm_kernel(const float* __restrict__ z,
                                                   const float* __restrict__ W1,
                                                   const float* __restrict__ b1,
                                                   u8* __restrict__ UVq) {
    __shared__ u16 Bs[128 * LDK];   // 128 x 136 bf16 (34.8 KB)

    int tid = threadIdx.x;

    // --- fused prep: thread t owns W1 row t (64 floats). ---
    // Bs[jj][k]: jj<64 -> W1[k][jj]; jj>=64 -> W1[128+k][jj-64].
    {
        int k   = tid & 127;
        int jjb = (tid >> 7) * 64;       // 0 or 64
        const float* wrow = W1 + tid * 64;
#pragma unroll
        for (int j = 0; j < 64; j += 4) {
            float4 w = *(const float4*)(wrow + j);
            // lanes write consecutive u16 (k=lane) -> 2 lanes/bank, free
            Bs[(jjb + j + 0) * LDK + k] = f2bf(w.x);
            Bs[(jjb + j + 1) * LDK + k] = f2bf(w.y);
            Bs[(jjb + j + 2) * LDK + k] = f2bf(w.z);
            Bs[(jjb + j + 3) * LDK + k] = f2bf(w.w);
        }
    }
    __syncthreads();

    int wave = tid >> 6;
    int lane = tid & 63;
    int quad = lane >> 4;
    int l16  = lane & 15;

    int gwid   = blockIdx.x * 4 + wave;
    const int NW = GEMM_BLOCKS * 4;    // 3128 waves
    const int NTILES = N_NODES / 16;   // 6250

    // bias for hidden rows nt*16 + quad*4 + r (U half only: nt<4)
    float4 bias4[4];
#pragma unroll
    for (int nt = 0; nt < 4; nt++) bias4[nt] = *(const float4*)(b1 + nt * 16 + quad * 4);

    for (int t = gwid; t < NTILES; t += NW) {
        const float* zrow = z + (size_t)(t * 16 + l16) * 128;

        f32x4 fa[8];
#pragma unroll
        for (int kb = 0; kb < 4; kb++) {
            fa[kb * 2]     = __builtin_nontemporal_load((const f32x4*)(zrow + kb * 32 + quad * 8));
            fa[kb * 2 + 1] = __builtin_nontemporal_load((const f32x4*)(zrow + kb * 32 + quad * 8 + 4));
        }
        bf16x8 afrag[4];
#pragma unroll
        for (int kb = 0; kb < 4; kb++) {
            union { bf16x8 v; u32 w[4]; } pk;
            f32x4 lo = fa[kb * 2], hi = fa[kb * 2 + 1];
            pk.w[0] = (u32)f2bf(lo[0]) | ((u32)f2bf(lo[1]) << 16);
            pk.w[1] = (u32)f2bf(lo[2]) | ((u32)f2bf(lo[3]) << 16);
            pk.w[2] = (u32)f2bf(hi[0]) | ((u32)f2bf(hi[1]) << 16);
            pk.w[3] = (u32)f2bf(hi[2]) | ((u32)f2bf(hi[3]) << 16);
            afrag[kb] = pk.v;
        }

        f32x4 acc[8];
        const f32x4 z4 = {0.f, 0.f, 0.f, 0.f};
#pragma unroll
        for (int i = 0; i < 8; i++) acc[i] = z4;

#pragma unroll
        for (int kb = 0; kb < 4; kb++) {
            int k0 = kb * 32 + quad * 8;
#pragma unroll
            for (int nt = 0; nt < 8; nt++) {
                bf16x8 bw = *(const bf16x8*)(Bs + (nt * 16 + l16) * LDK + k0);
                // swapped operands: D[hidden][node]
                acc[nt] = __builtin_amdgcn_mfma_f32_16x16x32_bf16(bw, afrag[kb], acc[nt], 0, 0, 0);
            }
        }

        // lane l16 = node t*16+l16; acc[nt][r] = hidden nt*16+quad*4+r
        u8* orow = UVq + (size_t)(t * 16 + l16) * 128;
#pragma unroll
        for (int nt = 0; nt < 8; nt++) {
            float x0 = acc[nt][0], x1 = acc[nt][1], x2 = acc[nt][2], x3 = acc[nt][3];
            if (nt < 4) {
                x0 += bias4[nt].x; x1 += bias4[nt].y; x2 += bias4[nt].z; x3 += bias4[nt].w;
            }
            u32 w = (u32)__builtin_amdgcn_cvt_pk_fp8_f32(x0, x1, 0, false);
            w = (u32)__builtin_amdgcn_cvt_pk_fp8_f32(x2, x3, (int)w, true);
            *(u32*)(orow + nt * 16 + quad * 4) = w;
        }
    }
}

// ---------------------------------------------------------------------------
// Kernel 2: edge MLP, byte-identical to round 1 (verified; pinned at the
// L2-miss-path ceiling ~3.3 TB/s -- insensitive to issue rate & occupancy).
// 4 lanes/edge, dwordx4 gathers, 128 edges/wave.
// ---------------------------------------------------------------------------
__global__ __launch_bounds__(256, 2) void edge_kernel(const int* __restrict__ ei,
                                                      const u8* __restrict__ UVq,
                                                      const float* __restrict__ W2,
                                                      const float* __restrict__ b2,
                                                      float* __restrict__ out) {
    int gwave = (blockIdx.x * 256 + threadIdx.x) >> 6;  // global wave id
    int lane  = threadIdx.x & 63;
    int sub   = lane >> 2;   // 0..15: edge slot within wave
    int c     = lane & 3;    // 16-B chunk id (16 fp8 cols) within the 64-col half

    // Per-lane W2 slice (cols c*16 .. c*16+15), loaded once.
    float w2r[16];
#pragma unroll
    for (int q = 0; q < 4; q++) {
        float4 t4 = *(const float4*)(W2 + c * 16 + q * 4);
        w2r[q * 4 + 0] = t4.x; w2r[q * 4 + 1] = t4.y;
        w2r[q * 4 + 2] = t4.z; w2r[q * 4 + 3] = t4.w;
    }
    float b2v = b2[0];

    int ebase = gwave * 128 + sub;

    // --- load cluster: 16 idx loads + 16 dwordx4 gathers before the fence ---
    int sB[BATCH], dB[BATCH];
#pragma unroll
    for (int j = 0; j < BATCH; j++) {
        int e = ebase + j * 16;
        sB[j] = __builtin_nontemporal_load(ei + e);
        dB[j] = __builtin_nontemporal_load(ei + N_EDGES + e);
    }
    uint4 aB[BATCH], bB[BATCH];
#pragma unroll
    for (int j = 0; j < BATCH; j++) {
        aB[j] = *(const uint4*)(UVq + (size_t)sB[j] * 128 + c * 16);        // U chunk
        bB[j] = *(const uint4*)(UVq + (size_t)dB[j] * 128 + 64 + c * 16);   // V chunk
    }
    __builtin_amdgcn_sched_barrier(0);

    // --- compute ---
#pragma unroll
    for (int j = 0; j < BATCH; j++) {
        u32 aw[4] = {aB[j].x, aB[j].y, aB[j].z, aB[j].w};
        u32 bw[4] = {bB[j].x, bB[j].y, bB[j].z, bB[j].w};
        float acc = 0.f;
#pragma unroll
        for (int i = 0; i < 4; i++) {
            // word-select must be an immediate: manual unroll (false=lo, true=hi)
            f32x2 uu0 = __builtin_amdgcn_cvt_pk_f32_fp8(aw[i], false);
            f32x2 vv0 = __builtin_amdgcn_cvt_pk_f32_fp8(bw[i], false);
            f32x2 uu1 = __builtin_amdgcn_cvt_pk_f32_fp8(aw[i], true);
            f32x2 vv1 = __builtin_amdgcn_cvt_pk_f32_fp8(bw[i], true);
            float h0 = fmaxf(uu0.x + vv0.x, 0.f);
            float h1 = fmaxf(uu0.y + vv0.y, 0.f);
            float h2 = fmaxf(uu1.x + vv1.x, 0.f);
            float h3 = fmaxf(uu1.y + vv1.y, 0.f);
            acc = fmaf(h0, w2r[i * 4 + 0], acc);
            acc = fmaf(h1, w2r[i * 4 + 1], acc);
            acc = fmaf(h2, w2r[i * 4 + 2], acc);
            acc = fmaf(h3, w2r[i * 4 + 3], acc);
        }
        // Butterfly reduce across the 4-lane group (xor 1,2 stay in-group).
        acc += __shfl_xor(acc, 1);
        acc += __shfl_xor(acc, 2);
        if (c == 0) {
            float x = acc + b2v;
            __builtin_nontemporal_store(1.f / (1.f + __expf(-x)), out + ebase + j * 16);
        }
    }
}

// ---------------------------------------------------------------------------
extern "C" void kernel_launch(void* const* d_in, const int* in_sizes, int n_in,
                              void* d_out, int out_size, void* d_ws, size_t ws_size,
                              hipStream_t stream) {
    const float* z  = (const float*)d_in[0];
    const int*   ei = (const int*)d_in[1];   // [2][N_EDGES]
    const float* W1 = (const float*)d_in[2]; // [256][64]
    const float* b1 = (const float*)d_in[3]; // [64]
    const float* W2 = (const float*)d_in[4]; // [64][1]
    const float* b2 = (const float*)d_in[5]; // [1]
    float* out = (float*)d_out;
    u8* UVq = (u8*)d_ws;                     // 12.8 MB fp8 table

    gemm_kernel<<<GEMM_BLOCKS, 256, 0, stream>>>(z, W1, b1, UVq);
    edge_kernel<<<EDGE_BLOCKS, 256, 0, stream>>>(ei, UVq, W2, b2, out);
}

// Round 5
// 152.232 us; speedup vs baseline: 1.0849x; 1.0849x over previous
//
#include <hip/hip_runtime.h>
#include <hip/hip_bf16.h>

#define N_NODES 100000
#define IN_DIM  128
#define HIDDEN  64
#define N_EDGES 1600000

typedef unsigned short u16;
typedef unsigned int   u32;
typedef unsigned char  u8;

typedef __attribute__((ext_vector_type(8))) short bf16x8;  // 8 bf16 in 4 VGPRs
typedef __attribute__((ext_vector_type(4))) float f32x4;
typedef __attribute__((ext_vector_type(2))) float f32x2;

__device__ __forceinline__ u16 f2bf(float f) {
    // round-to-nearest-even fp32 -> bf16
    u32 u = __float_as_uint(f);
    u32 r = 0x7FFFu + ((u >> 16) & 1u);
    u += r;
    return (u16)(u >> 16);
}

__device__ __forceinline__ u8 f2fp8(float f) {
    // fp32 -> OCP e4m3 via HW cvt (RNE, satfinite)
    u32 p = (u32)__builtin_amdgcn_cvt_pk_fp8_f32(f, f, 0, false);
    return (u8)(p & 0xFF);
}

// ---------------------------------------------------------------------------
// Kernel 1: build WcatT[jj][k] (bf16, [128][128]) from W1 (fp32, [256][64]).
// ---------------------------------------------------------------------------
__global__ __launch_bounds__(256) void prep_kernel(const float* __restrict__ W1,
                                                   u16* __restrict__ WcatT) {
    int idx = blockIdx.x * 256 + threadIdx.x;   // 0..16383
    int jj = idx >> 7;
    int k  = idx & 127;
    float v = (jj < 64) ? W1[k * 64 + jj] : W1[(128 + k) * 64 + (jj - 64)];
    WcatT[idx] = f2bf(v);
}

// ---------------------------------------------------------------------------
// Kernel 2: persistent grid-stride GEMM (bf16 MFMA), epilogue quantizes the
// pre-activations to fp8 e4m3: UVq[node][128] bytes, U=cols 0..63 (1 cache
// line), V=cols 64..127 (1 line). Halves edge-phase line traffic.
// ---------------------------------------------------------------------------
#define LDK 136   // 128 + 8 bf16 pad -> row stride 272 B (16B-aligned)
#define GEMM_BLOCKS 625

__global__ __launch_bounds__(256) void gemm_kernel(const float* __restrict__ z,
                                                   const u16* __restrict__ WcatT,
                                                   const float* __restrict__ b1,
                                                   u8* __restrict__ UVq) {
    __shared__ u16 Bs[128 * LDK];   // 128 x 136 bf16 (34.8 KB)

    int tid = threadIdx.x;
    for (int c = tid; c < 128 * 16; c += 256) {
        int row = c >> 4, cc = c & 15;
        *(uint4*)(Bs + row * LDK + cc * 8) = *(const uint4*)(WcatT + row * 128 + cc * 8);
    }
    __syncthreads();

    int wave = tid >> 6;
    int lane = tid & 63;
    int quad = lane >> 4;
    int l16  = lane & 15;

    int gwid   = blockIdx.x * 4 + wave;
    int nwaves = GEMM_BLOCKS * 4;
    const int NTILES = N_NODES / 16;   // 6250

    float bias[4];
#pragma unroll
    for (int nt = 0; nt < 4; nt++) bias[nt] = b1[nt * 16 + l16];

    for (int t = gwid; t < NTILES; t += nwaves) {
        const float* zrow = z + (size_t)(t * 16 + l16) * 128;

        float4 fa[8];
#pragma unroll
        for (int kb = 0; kb < 4; kb++) {
            fa[kb * 2]     = *(const float4*)(zrow + kb * 32 + quad * 8);
            fa[kb * 2 + 1] = *(const float4*)(zrow + kb * 32 + quad * 8 + 4);
        }
        bf16x8 afrag[4];
#pragma unroll
        for (int kb = 0; kb < 4; kb++) {
            union { bf16x8 v; u32 w[4]; } pk;
            float4 lo = fa[kb * 2], hi = fa[kb * 2 + 1];
            pk.w[0] = (u32)f2bf(lo.x) | ((u32)f2bf(lo.y) << 16);
            pk.w[1] = (u32)f2bf(lo.z) | ((u32)f2bf(lo.w) << 16);
            pk.w[2] = (u32)f2bf(hi.x) | ((u32)f2bf(hi.y) << 16);
            pk.w[3] = (u32)f2bf(hi.z) | ((u32)f2bf(hi.w) << 16);
            afrag[kb] = pk.v;
        }

        f32x4 acc[8];
        const f32x4 z4 = {0.f, 0.f, 0.f, 0.f};
#pragma unroll
        for (int i = 0; i < 8; i++) acc[i] = z4;

#pragma unroll
        for (int kb = 0; kb < 4; kb++) {
            int k0 = kb * 32 + quad * 8;
#pragma unroll
            for (int nt = 0; nt < 8; nt++) {
                bf16x8 b = *(const bf16x8*)(Bs + (nt * 16 + l16) * LDK + k0);
                acc[nt] = __builtin_amdgcn_mfma_f32_16x16x32_bf16(afrag[kb], b, acc[nt], 0, 0, 0);
            }
        }

        // Epilogue: D layout col=lane&15, row=quad*4+reg; quantize to e4m3
#pragma unroll
        for (int nt = 0; nt < 8; nt++) {
            float bb = (nt < 4) ? bias[nt] : 0.f;
#pragma unroll
            for (int r = 0; r < 4; r++) {
                int row = t * 16 + quad * 4 + r;
                UVq[(size_t)row * 128 + nt * 16 + l16] = f2fp8(acc[nt][r] + bb);
            }
        }
    }
}

// ---------------------------------------------------------------------------
// Kernel 3: lane-cooperative edge MLP over the fp8 UV table.
// 8 lanes per edge, each lane owns 8 consecutive hidden cols (8 B of U, 8 B of
// V). Per 8-lane group: U row = 1 cache line, V row = 1 line (bf16 needed 2+2).
// BATCH=8 edges: all 16 idx loads + 16 gathers issued before a scheduling
// fence, forcing many outstanding vmem per thread (round 2/3 got ~2).
// ---------------------------------------------------------------------------
#define BATCH 8   // edges per wave = 8 subs * 8 batch = 64

__global__ __launch_bounds__(256, 2) void edge_kernel(const int* __restrict__ ei,
                                                      const u8* __restrict__ UVq,
                                                      const float* __restrict__ W2,
                                                      const float* __restrict__ b2,
                                                      float* __restrict__ out) {
    int gwave = (blockIdx.x * 256 + threadIdx.x) >> 6;  // global wave id
    int lane  = threadIdx.x & 63;
    int sub   = lane >> 3;   // 0..7: edge slot within wave
    int c     = lane & 7;    // 8-B chunk id (8 fp8 cols) within the 64-col half

    // Per-lane W2 slice (cols c*8 .. c*8+7), loaded once.
    float4 w2a = *(const float4*)(W2 + c * 8);
    float4 w2b = *(const float4*)(W2 + c * 8 + 4);
    float w2r[8] = {w2a.x, w2a.y, w2a.z, w2a.w, w2b.x, w2b.y, w2b.z, w2b.w};
    float b2v = b2[0];

    int ebase = gwave * 64 + sub;

    // --- load cluster: 16 idx loads + 16 gathers, all before the fence ---
    int sB[BATCH], dB[BATCH];
#pragma unroll
    for (int j = 0; j < BATCH; j++) {
        int e = ebase + j * 8;
        sB[j] = __builtin_nontemporal_load(ei + e);
        dB[j] = __builtin_nontemporal_load(ei + N_EDGES + e);
    }
    uint2 aB[BATCH], bB[BATCH];
#pragma unroll
    for (int j = 0; j < BATCH; j++) {
        aB[j] = *(const uint2*)(UVq + (size_t)sB[j] * 128 + c * 8);        // U chunk
        bB[j] = *(const uint2*)(UVq + (size_t)dB[j] * 128 + 64 + c * 8);   // V chunk
    }
    __builtin_amdgcn_sched_barrier(0);

    // --- compute ---
#pragma unroll
    for (int j = 0; j < BATCH; j++) {
        u32 aw[2] = {aB[j].x, aB[j].y};
        u32 bw[2] = {bB[j].x, bB[j].y};
        float acc = 0.f;
#pragma unroll
        for (int i = 0; i < 2; i++) {
            // word-select must be an immediate: manual unroll (false=lo, true=hi)
            f32x2 uu0 = __builtin_amdgcn_cvt_pk_f32_fp8(aw[i], false);
            f32x2 vv0 = __builtin_amdgcn_cvt_pk_f32_fp8(bw[i], false);
            f32x2 uu1 = __builtin_amdgcn_cvt_pk_f32_fp8(aw[i], true);
            f32x2 vv1 = __builtin_amdgcn_cvt_pk_f32_fp8(bw[i], true);
            float h0 = fmaxf(uu0.x + vv0.x, 0.f);
            float h1 = fmaxf(uu0.y + vv0.y, 0.f);
            float h2 = fmaxf(uu1.x + vv1.x, 0.f);
            float h3 = fmaxf(uu1.y + vv1.y, 0.f);
            acc = fmaf(h0, w2r[i * 4 + 0], acc);
            acc = fmaf(h1, w2r[i * 4 + 1], acc);
            acc = fmaf(h2, w2r[i * 4 + 2], acc);
            acc = fmaf(h3, w2r[i * 4 + 3], acc);
        }
        // Butterfly reduce across the 8-lane group (xor 1,2,4 stay in-group).
        acc += __shfl_xor(acc, 1);
        acc += __shfl_xor(acc, 2);
        acc += __shfl_xor(acc, 4);
        if (c == 0) {
            float x = acc + b2v;
            __builtin_nontemporal_store(1.f / (1.f + __expf(-x)), out + ebase + j * 8);
        }
    }
}

// ---------------------------------------------------------------------------
extern "C" void kernel_launch(void* const* d_in, const int* in_sizes, int n_in,
                              void* d_out, int out_size, void* d_ws, size_t ws_size,
                              hipStream_t stream) {
    const float* z  = (const float*)d_in[0];
    const int*   ei = (const int*)d_in[1];   // [2][N_EDGES]
    const float* W1 = (const float*)d_in[2]; // [256][64]
    const float* b1 = (const float*)d_in[3]; // [64]
    const float* W2 = (const float*)d_in[4]; // [64][1]
    const float* b2 = (const float*)d_in[5]; // [1]
    float* out = (float*)d_out;

    u16* WcatT = (u16*)d_ws;                           // 32 KB
    u8*  UVq   = (u8*)((char*)d_ws + 65536);           // 12.8 MB fp8 table

    prep_kernel<<<64, 256, 0, stream>>>(W1, WcatT);
    gemm_kernel<<<GEMM_BLOCKS, 256, 0, stream>>>(z, WcatT, b1, UVq);
    // 1.6M edges / (64 edges per wave) = 25000 waves = 6250 blocks of 4 waves
    edge_kernel<<<6250, 256, 0, stream>>>(ei, UVq, W2, b2, out);
}